// Round 5
// baseline (178.862 us; speedup 1.0000x reference)
//
#include <hip/hip_runtime.h>

#define NPOS 32768   // 32 * 32 * 32 positions
#define DDIM 256
#define KCODES 1024

typedef __attribute__((ext_vector_type(8))) short bf16x8;
typedef __attribute__((ext_vector_type(4))) float f32x4;
typedef unsigned long long u64;

// ---- fp32 ops with anti-contraction barriers (replicate numpy rounding) ----
__device__ __forceinline__ float sqr_rn(float x) {
    float r = x * x;
    asm volatile("" : "+v"(r));
    return r;
}
__device__ __forceinline__ float add_rn(float a, float b) {
    float r = a + b;
    asm volatile("" : "+v"(r));
    return r;
}

// fp32 -> bf16 round-to-nearest-even (verbatim from verified kernel)
__device__ __forceinline__ unsigned short f2bf(float x) {
    unsigned u = __float_as_uint(x);
    return (unsigned short)((u + 0x7fffu + ((u >> 16) & 1u)) >> 16);
}

// monotone pack: float score -> order-preserving u32, | code in low bits
__device__ __forceinline__ u64 packm(float s, int code) {
    unsigned b = __float_as_uint(s);
    unsigned mm = ((unsigned)((int)b >> 31)) | 0x80000000u;
    return ((u64)(b ^ mm) << 32) | (unsigned)code;
}

// ---------------- wprep: wsq + W bf16 tiled (verbatim from verified prep) ----------------
__global__ __launch_bounds__(256) void wprep(const float* __restrict__ W,
                                             float* __restrict__ wsq,
                                             unsigned short* __restrict__ wb16t) {
    const int t   = threadIdx.x;
    const int bid = blockIdx.x;
    const int row = bid * 16 + (t >> 4);
    const int j   = t & 15;
    const float* base = W + row * DDIM + (j & 7) + (j >> 3) * 128;
    float r = sqr_rn(base[0]);
#pragma unroll
    for (int i = 1; i < 16; ++i) r = add_rn(r, sqr_rn(base[i * 8]));
#pragma unroll
    for (int m = 1; m <= 8; m <<= 1) r = add_rn(r, __shfl_xor(r, m));
    if (j == 0) wsq[row] = r;
#pragma unroll
    for (int jj = 0; jj < 2; ++jj) {
        const int u  = t + jj * 256;      // 512 units = 16 rows x 32 k8
        const int n  = bid * 16 + (u >> 5);
        const int k8 = u & 31;
        const float4 f0 = *(const float4*)&W[n * DDIM + k8 * 8];
        const float4 f1 = *(const float4*)&W[n * DDIM + k8 * 8 + 4];
        bf16x8 o;
        o[0] = (short)f2bf(f0.x); o[1] = (short)f2bf(f0.y);
        o[2] = (short)f2bf(f0.z); o[3] = (short)f2bf(f0.w);
        o[4] = (short)f2bf(f1.x); o[5] = (short)f2bf(f1.y);
        o[6] = (short)f2bf(f1.z); o[7] = (short)f2bf(f1.w);
        const int kk = k8 >> 2, kq = k8 & 3;
        *(bf16x8*)&wb16t[(n >> 8) * 65536 + kk * 8192 + kq * 2048 + (n & 255) * 8] = o;
    }
}

// ---------------- fused: z->bf16 LDS stage + MFMA GEMM + top-2 + exact rescore ----------------
// Grid 1024: one block per 32 positions, 256 threads (4 waves).
// LDS 18.7 KB + VGPR<=85 (__launch_bounds__(256,6)) -> 6 blocks/CU resident
// (24 waves/CU): +50% TLP to cover the L2/LDS latency chains that r4 showed
// exposed (34% issue-active, nothing saturated).
// Phase A: stage z slice [32 pos x 256 d] as bf16 A-tile in LDS (same tiling
//          and f2bf as verified -> bit-identical MFMA inputs).
// Phase B: 4 n-panels of 256 codes; B-frags ping-pong register double-buffer
//          (kk unroll-by-2, NO bfr=bnx copies -- r4 spent 512 v_movs/thread
//          there); MFMA order kk=0..7 preserved -> bit-identical accumulate.
//          Running per-lane top-2 across panels; ONE tournament at the end.
// Phase C: numpy-bit-exact rescore (verbatim arithmetic) in TWO 16-position
//          chunks so the fp32 tile is 16.6 KB instead of 33.3 KB.
#define ZS 260   // floats per Zs row (bank-spread, as verified)
__global__ __launch_bounds__(256, 6)
void vq_fused(const float* __restrict__ z,
              const float* __restrict__ W,
              const float* __restrict__ wsq,
              const unsigned short* __restrict__ wb16t,
              int* __restrict__ out) {
    union Sm {
        unsigned short At[8192];    // 16 KB bf16 A-tile [k8(32)][m(32)][e(8)]
        float          Zs[16 * ZS]; // 16.6 KB fp32 rescore tile (Phase C only)
    };
    __shared__ Sm  sm;
    __shared__ u64 redL[32 * 8];    // 2 KB: [row][wave][2] = 8 candidates/row

    const int t   = threadIdx.x;
    const int bid = blockIdx.x;
    const int img = bid >> 5;           // 32 blocks per image
    const int p0  = (bid & 31) * 32;    // first position within image

    // ---- Phase A: z -> bf16 A-tile in LDS ----
    {
        const float* zbase = z + img * (DDIM * 1024) + p0;
#pragma unroll
        for (int jj = 0; jj < 4; ++jj) {
            const int u_ = t + jj * 256;     // 1024 units = 32 m x 32 k8
            const int m  = u_ & 31;
            const int k8 = u_ >> 5;
            const float* src = zbase + k8 * 8192 + m;   // d = k8*8+e, stride 1024 floats
            bf16x8 o;
#pragma unroll
            for (int e = 0; e < 8; ++e) o[e] = (short)f2bf(src[e * 1024]);
            *(bf16x8*)&sm.At[k8 * 256 + m * 8] = o;     // byte addr k8*512 + m*16
        }
    }
    __syncthreads();

    // ---- Phase B: GEMM over 4 n-panels, running per-lane top-2 ----
    const int w  = t >> 6;          // wave = col quadrant 0..3
    const int l  = t & 63;
    const int ln = l & 15;
    const int q  = l >> 4;
    const int nw = w * 64;

    const char* aBase = (const char*)sm.At + q * 512 + ln * 16;
    const char* bBase = (const char*)wb16t + q * 4096 + (nw + ln) * 16;

    // running top-2 state per (mf,reg): lane's best over 4 panels x 4 nf
    float s0[2][4], s1[2][4];
    int   i0[2][4], i1[2][4];
#pragma unroll
    for (int mf = 0; mf < 2; ++mf)
#pragma unroll
        for (int reg = 0; reg < 4; ++reg) {
            s0[mf][reg] = 1e30f; s1[mf][reg] = 1e30f;
            i0[mf][reg] = 0;     i1[mf][reg] = 0;
        }

#pragma unroll 1
    for (int nblk = 0; nblk < 4; ++nblk) {
        const int n0 = nblk * 256;
        float wq[4];
#pragma unroll
        for (int nf = 0; nf < 4; ++nf) wq[nf] = wsq[n0 + nw + nf * 16 + ln];

        f32x4 acc[2][4];
#pragma unroll
        for (int a = 0; a < 2; ++a)
#pragma unroll
            for (int b = 0; b < 4; ++b) acc[a][b] = (f32x4)(0.f);

        const char* bP = bBase + nblk * 131072;
        bf16x8 bA[4], bB[4];
#pragma unroll
        for (int nf = 0; nf < 4; ++nf) bA[nf] = *(const bf16x8*)(bP + nf * 256);

        // kk ping-pong: even kk uses bA (prefetch kk+1 -> bB),
        //               odd  kk uses bB (prefetch kk+2 -> bA). Order kk=0..7.
#pragma unroll 1
        for (int kk2 = 0; kk2 < 4; ++kk2) {
            const int kkE = kk2 * 2;
            // prefetch odd kk
#pragma unroll
            for (int nf = 0; nf < 4; ++nf)
                bB[nf] = *(const bf16x8*)(bP + (kkE + 1) * 16384 + nf * 256);
            {
                bf16x8 afr[2];
#pragma unroll
                for (int mf = 0; mf < 2; ++mf)
                    afr[mf] = *(const bf16x8*)(aBase + kkE * 2048 + mf * 256);
#pragma unroll
                for (int nf = 0; nf < 4; ++nf)
#pragma unroll
                    for (int mf = 0; mf < 2; ++mf)
                        acc[mf][nf] = __builtin_amdgcn_mfma_f32_16x16x32_bf16(
                            afr[mf], bA[nf], acc[mf][nf], 0, 0, 0);
            }
            // prefetch next even kk
            if (kk2 < 3) {
#pragma unroll
                for (int nf = 0; nf < 4; ++nf)
                    bA[nf] = *(const bf16x8*)(bP + (kkE + 2) * 16384 + nf * 256);
            }
            {
                bf16x8 afr[2];
#pragma unroll
                for (int mf = 0; mf < 2; ++mf)
                    afr[mf] = *(const bf16x8*)(aBase + (kkE + 1) * 2048 + mf * 256);
#pragma unroll
                for (int nf = 0; nf < 4; ++nf)
#pragma unroll
                    for (int mf = 0; mf < 2; ++mf)
                        acc[mf][nf] = __builtin_amdgcn_mfma_f32_16x16x32_bf16(
                            afr[mf], bB[nf], acc[mf][nf], 0, 0, 0);
            }
        }

        // scan: score = wsq - 2*acc (row-const zsq dropped); update running top-2
#pragma unroll
        for (int mf = 0; mf < 2; ++mf) {
#pragma unroll
            for (int reg = 0; reg < 4; ++reg) {
#pragma unroll
                for (int nf = 0; nf < 4; ++nf) {
                    const float s  = fmaf(-2.f, acc[mf][nf][reg], wq[nf]);
                    const int   cc = n0 + nw + nf * 16 + ln;
                    if (s < s0[mf][reg]) {
                        s1[mf][reg] = s0[mf][reg]; i1[mf][reg] = i0[mf][reg];
                        s0[mf][reg] = s;           i0[mf][reg] = cc;
                    } else if (s < s1[mf][reg]) {
                        s1[mf][reg] = s;           i1[mf][reg] = cc;
                    }
                }
            }
        }
    }

    // ---- ONE tournament per (mf,reg): exact top-2 across the 16-lane group ----
#pragma unroll
    for (int mf = 0; mf < 2; ++mf) {
#pragma unroll
        for (int reg = 0; reg < 4; ++reg) {
            const int row = mf * 16 + q * 4 + reg;
            u64 c0 = packm(s0[mf][reg], i0[mf][reg]);
            u64 c1 = packm(s1[mf][reg], i1[mf][reg]);
#pragma unroll
            for (int m = 1; m <= 8; m <<= 1) {
                const u64 o0 = __shfl_xor(c0, m);
                const u64 o1 = __shfl_xor(c1, m);
                const u64 hi = (c0 < o0) ? o0 : c0;
                c0 = (c0 < o0) ? c0 : o0;
                const u64 lo = (c1 < o1) ? c1 : o1;
                c1 = (hi < lo) ? hi : lo;
            }
            if (ln == 0) {
                redL[row * 8 + w * 2]     = c0;
                redL[row * 8 + w * 2 + 1] = c1;
            }
        }
    }
    __syncthreads();   // publishes redL; all At reads complete -> Zs may overwrite

    // ---- Phase C: exact numpy-bit rescore (verbatim arithmetic), 2 x 16 pos ----
    const float* zimg = z + img * (DDIM * 1024) + p0;
#pragma unroll 1
    for (int c = 0; c < 2; ++c) {
        // stage 16 positions x 256 d as fp32 [16][ZS]
#pragma unroll
        for (int jj = 0; jj < 4; ++jj) {
            const int f4 = t + jj * 256;     // 0..1023
            const int d  = f4 >> 2;          // 0..255
            const int p4 = f4 & 3;           // float4 group (4 positions)
            const float4 v = *(const float4*)&zimg[d * 1024 + c * 16 + p4 * 4];
            sm.Zs[(p4 * 4 + 0) * ZS + d] = v.x;
            sm.Zs[(p4 * 4 + 1) * ZS + d] = v.y;
            sm.Zs[(p4 * 4 + 2) * ZS + d] = v.z;
            sm.Zs[(p4 * 4 + 3) * ZS + d] = v.w;
        }
        __syncthreads();
        if (t < 128) {
            const int pl = t >> 3, slot = t & 7;
            const float* zr = &sm.Zs[pl * ZS];

            // numpy-exact zsq: slot chains + xor butterfly, halves joined last
            float h0 = sqr_rn(zr[slot]);
            float h1 = sqr_rn(zr[128 + slot]);
#pragma unroll
            for (int i = 1; i < 16; ++i) {
                h0 = add_rn(h0, sqr_rn(zr[slot + 8 * i]));
                h1 = add_rn(h1, sqr_rn(zr[128 + slot + 8 * i]));
            }
#pragma unroll
            for (int m = 1; m <= 4; m <<= 1) {
                h0 = add_rn(h0, __shfl_xor(h0, m));
                h1 = add_rn(h1, __shfl_xor(h1, m));
            }
            const float zq = add_rn(h0, h1);

            const int code = (int)(unsigned)(redL[(c * 16 + pl) * 8 + slot] & 0xffffffffULL);
            const float* wr = W + code * DDIM;
            // sequential fma chain over d ascending — bit-identical to verified path
            float M = 0.f;
#pragma unroll 8
            for (int d4 = 0; d4 < 64; ++d4) {
                const float4 zv = *(const float4*)&zr[d4 * 4];
                const float4 wv = *(const float4*)&wr[d4 * 4];
                M = fmaf(zv.x, wv.x, M);
                M = fmaf(zv.y, wv.y, M);
                M = fmaf(zv.z, wv.z, M);
                M = fmaf(zv.w, wv.w, M);
            }
            const float s = add_rn(fmaf(-2.f, M, zq), wsq[code]);
            u64 v = ((u64)__float_as_uint(s) << 32) | (unsigned)code;
#pragma unroll
            for (int m = 1; m <= 4; m <<= 1) {
                const u64 o = __shfl_xor(v, m);
                if (o < v) v = o;
            }
            if (slot == 0) out[img * 1024 + p0 + c * 16 + pl] = (int)(unsigned)(v & 0xffffffffULL);
        }
        __syncthreads();   // protect Zs reuse for next chunk
    }
}

extern "C" void kernel_launch(void* const* d_in, const int* in_sizes, int n_in,
                              void* d_out, int out_size, void* d_ws, size_t ws_size,
                              hipStream_t stream) {
    const float* z = (const float*)d_in[0];   // [32, 256, 32, 32] NCHW
    const float* W = (const float*)d_in[1];   // [1024, 256]
    int* out = (int*)d_out;                   // [32768] int32 indices

    char* ws = (char*)d_ws;
    float*          wsq   = (float*)ws;                  //   4 KB @ 0
    unsigned short* wb16t = (unsigned short*)(ws + 4096); // 512 KB

    wprep<<<KCODES / 16, 256, 0, stream>>>(W, wsq, wb16t);
    vq_fused<<<NPOS / 32, 256, 0, stream>>>(z, W, wsq, wb16t, out);
}

// Round 6
// 153.016 us; speedup vs baseline: 1.1689x; 1.1689x over previous
//
#include <hip/hip_runtime.h>

#define NPOS 32768   // 32 * 32 * 32 positions
#define DDIM 256
#define KCODES 1024

typedef __attribute__((ext_vector_type(8))) short bf16x8;
typedef __attribute__((ext_vector_type(4))) float f32x4;
typedef unsigned long long u64;

// ---- fp32 ops with anti-contraction barriers (replicate numpy rounding) ----
__device__ __forceinline__ float sqr_rn(float x) {
    float r = x * x;
    asm volatile("" : "+v"(r));
    return r;
}
__device__ __forceinline__ float add_rn(float a, float b) {
    float r = a + b;
    asm volatile("" : "+v"(r));
    return r;
}

// fp32 -> bf16 round-to-nearest-even (verbatim from verified kernel)
__device__ __forceinline__ unsigned short f2bf(float x) {
    unsigned u = __float_as_uint(x);
    return (unsigned short)((u + 0x7fffu + ((u >> 16) & 1u)) >> 16);
}

// monotone pack: float score -> order-preserving u32, | code in low bits
__device__ __forceinline__ u64 packm(float s, int code) {
    unsigned b = __float_as_uint(s);
    unsigned mm = ((unsigned)((int)b >> 31)) | 0x80000000u;
    return ((u64)(b ^ mm) << 32) | (unsigned)code;
}

// ---------------- wprep: wsq + W bf16 tiled (verbatim from verified prep) ----------------
__global__ __launch_bounds__(256) void wprep(const float* __restrict__ W,
                                             float* __restrict__ wsq,
                                             unsigned short* __restrict__ wb16t) {
    const int t   = threadIdx.x;
    const int bid = blockIdx.x;
    const int row = bid * 16 + (t >> 4);
    const int j   = t & 15;
    const float* base = W + row * DDIM + (j & 7) + (j >> 3) * 128;
    float r = sqr_rn(base[0]);
#pragma unroll
    for (int i = 1; i < 16; ++i) r = add_rn(r, sqr_rn(base[i * 8]));
#pragma unroll
    for (int m = 1; m <= 8; m <<= 1) r = add_rn(r, __shfl_xor(r, m));
    if (j == 0) wsq[row] = r;
#pragma unroll
    for (int jj = 0; jj < 2; ++jj) {
        const int u  = t + jj * 256;      // 512 units = 16 rows x 32 k8
        const int n  = bid * 16 + (u >> 5);
        const int k8 = u & 31;
        const float4 f0 = *(const float4*)&W[n * DDIM + k8 * 8];
        const float4 f1 = *(const float4*)&W[n * DDIM + k8 * 8 + 4];
        bf16x8 o;
        o[0] = (short)f2bf(f0.x); o[1] = (short)f2bf(f0.y);
        o[2] = (short)f2bf(f0.z); o[3] = (short)f2bf(f0.w);
        o[4] = (short)f2bf(f1.x); o[5] = (short)f2bf(f1.y);
        o[6] = (short)f2bf(f1.z); o[7] = (short)f2bf(f1.w);
        const int kk = k8 >> 2, kq = k8 & 3;
        *(bf16x8*)&wb16t[(n >> 8) * 65536 + kk * 8192 + kq * 2048 + (n & 255) * 8] = o;
    }
}

// ---------------- fused: z->bf16 LDS stage + MFMA GEMM + top-2 + exact rescore ----------------
// Grid 1024: one block per 32 positions, 256 threads (4 waves).
// LDS 18.9 KB; NO waves-per-EU cap (r5's __launch_bounds__(256,6) forced
// VGPR 84->40 with 370 MB of scratch spill traffic -- WRITE_SIZE 217 MB).
// Natural VGPR ~90 -> 5 blocks/CU (20 waves), zero spill.
// Phase A: stage z slice [32 pos x 256 d] as bf16 A-tile in LDS (same tiling
//          and f2bf as verified -> bit-identical MFMA inputs).
// Phase B: 4 n-panels of 256 codes; B-frags ping-pong register double-buffer
//          (kk unroll-by-2, no bfr=bnx copies); MFMA order kk=0..7 preserved
//          -> bit-identical accumulate. Running per-lane top-2 across panels;
//          ONE 4-level tournament at the end -> 8 candidates/row in redL.
// Phase C: numpy-bit-exact rescore (verbatim arithmetic) in TWO 16-position
//          chunks so the fp32 tile is 16.6 KB instead of 33.3 KB.
#define ZS 260   // floats per Zs row (bank-spread, as verified)
__global__ __launch_bounds__(256)
void vq_fused(const float* __restrict__ z,
              const float* __restrict__ W,
              const float* __restrict__ wsq,
              const unsigned short* __restrict__ wb16t,
              int* __restrict__ out) {
    union Sm {
        unsigned short At[8192];    // 16 KB bf16 A-tile [k8(32)][m(32)][e(8)]
        float          Zs[16 * ZS]; // 16.6 KB fp32 rescore tile (Phase C only)
    };
    __shared__ Sm  sm;
    __shared__ u64 redL[32 * 8];    // 2 KB: [row][wave][2] = 8 candidates/row

    const int t   = threadIdx.x;
    const int bid = blockIdx.x;
    const int img = bid >> 5;           // 32 blocks per image
    const int p0  = (bid & 31) * 32;    // first position within image

    // ---- Phase A: z -> bf16 A-tile in LDS ----
    {
        const float* zbase = z + img * (DDIM * 1024) + p0;
#pragma unroll
        for (int jj = 0; jj < 4; ++jj) {
            const int u_ = t + jj * 256;     // 1024 units = 32 m x 32 k8
            const int m  = u_ & 31;
            const int k8 = u_ >> 5;
            const float* src = zbase + k8 * 8192 + m;   // d = k8*8+e, stride 1024 floats
            bf16x8 o;
#pragma unroll
            for (int e = 0; e < 8; ++e) o[e] = (short)f2bf(src[e * 1024]);
            *(bf16x8*)&sm.At[k8 * 256 + m * 8] = o;     // byte addr k8*512 + m*16
        }
    }
    __syncthreads();

    // ---- Phase B: GEMM over 4 n-panels, running per-lane top-2 ----
    const int w  = t >> 6;          // wave = col quadrant 0..3
    const int l  = t & 63;
    const int ln = l & 15;
    const int q  = l >> 4;
    const int nw = w * 64;

    const char* aBase = (const char*)sm.At + q * 512 + ln * 16;
    const char* bBase = (const char*)wb16t + q * 4096 + (nw + ln) * 16;

    // running top-2 state per (mf,reg): lane's best over 4 panels x 4 nf
    float s0[2][4], s1[2][4];
    int   i0[2][4], i1[2][4];
#pragma unroll
    for (int mf = 0; mf < 2; ++mf)
#pragma unroll
        for (int reg = 0; reg < 4; ++reg) {
            s0[mf][reg] = 1e30f; s1[mf][reg] = 1e30f;
            i0[mf][reg] = 0;     i1[mf][reg] = 0;
        }

#pragma unroll 1
    for (int nblk = 0; nblk < 4; ++nblk) {
        const int n0 = nblk * 256;
        float wq[4];
#pragma unroll
        for (int nf = 0; nf < 4; ++nf) wq[nf] = wsq[n0 + nw + nf * 16 + ln];

        f32x4 acc[2][4];
#pragma unroll
        for (int a = 0; a < 2; ++a)
#pragma unroll
            for (int b = 0; b < 4; ++b) acc[a][b] = (f32x4)(0.f);

        const char* bP = bBase + nblk * 131072;
        bf16x8 bA[4], bB[4];
#pragma unroll
        for (int nf = 0; nf < 4; ++nf) bA[nf] = *(const bf16x8*)(bP + nf * 256);

        // kk ping-pong: even kk uses bA (prefetch kk+1 -> bB),
        //               odd  kk uses bB (prefetch kk+2 -> bA). Order kk=0..7.
#pragma unroll 1
        for (int kk2 = 0; kk2 < 4; ++kk2) {
            const int kkE = kk2 * 2;
            // prefetch odd kk
#pragma unroll
            for (int nf = 0; nf < 4; ++nf)
                bB[nf] = *(const bf16x8*)(bP + (kkE + 1) * 16384 + nf * 256);
            {
                bf16x8 afr[2];
#pragma unroll
                for (int mf = 0; mf < 2; ++mf)
                    afr[mf] = *(const bf16x8*)(aBase + kkE * 2048 + mf * 256);
#pragma unroll
                for (int nf = 0; nf < 4; ++nf)
#pragma unroll
                    for (int mf = 0; mf < 2; ++mf)
                        acc[mf][nf] = __builtin_amdgcn_mfma_f32_16x16x32_bf16(
                            afr[mf], bA[nf], acc[mf][nf], 0, 0, 0);
            }
            // prefetch next even kk
            if (kk2 < 3) {
#pragma unroll
                for (int nf = 0; nf < 4; ++nf)
                    bA[nf] = *(const bf16x8*)(bP + (kkE + 2) * 16384 + nf * 256);
            }
            {
                bf16x8 afr[2];
#pragma unroll
                for (int mf = 0; mf < 2; ++mf)
                    afr[mf] = *(const bf16x8*)(aBase + (kkE + 1) * 2048 + mf * 256);
#pragma unroll
                for (int nf = 0; nf < 4; ++nf)
#pragma unroll
                    for (int mf = 0; mf < 2; ++mf)
                        acc[mf][nf] = __builtin_amdgcn_mfma_f32_16x16x32_bf16(
                            afr[mf], bB[nf], acc[mf][nf], 0, 0, 0);
            }
        }

        // scan: score = wsq - 2*acc (row-const zsq dropped); update running top-2
#pragma unroll
        for (int mf = 0; mf < 2; ++mf) {
#pragma unroll
            for (int reg = 0; reg < 4; ++reg) {
#pragma unroll
                for (int nf = 0; nf < 4; ++nf) {
                    const float s  = fmaf(-2.f, acc[mf][nf][reg], wq[nf]);
                    const int   cc = n0 + nw + nf * 16 + ln;
                    if (s < s0[mf][reg]) {
                        s1[mf][reg] = s0[mf][reg]; i1[mf][reg] = i0[mf][reg];
                        s0[mf][reg] = s;           i0[mf][reg] = cc;
                    } else if (s < s1[mf][reg]) {
                        s1[mf][reg] = s;           i1[mf][reg] = cc;
                    }
                }
            }
        }
    }

    // ---- ONE tournament per (mf,reg): exact top-2 across the 16-lane group ----
#pragma unroll
    for (int mf = 0; mf < 2; ++mf) {
#pragma unroll
        for (int reg = 0; reg < 4; ++reg) {
            const int row = mf * 16 + q * 4 + reg;
            u64 c0 = packm(s0[mf][reg], i0[mf][reg]);
            u64 c1 = packm(s1[mf][reg], i1[mf][reg]);
#pragma unroll
            for (int m = 1; m <= 8; m <<= 1) {
                const u64 o0 = __shfl_xor(c0, m);
                const u64 o1 = __shfl_xor(c1, m);
                const u64 hi = (c0 < o0) ? o0 : c0;
                c0 = (c0 < o0) ? c0 : o0;
                const u64 lo = (c1 < o1) ? c1 : o1;
                c1 = (hi < lo) ? hi : lo;
            }
            if (ln == 0) {
                redL[row * 8 + w * 2]     = c0;
                redL[row * 8 + w * 2 + 1] = c1;
            }
        }
    }
    __syncthreads();   // publishes redL; all At reads complete -> Zs may overwrite

    // ---- Phase C: exact numpy-bit rescore (verbatim arithmetic), 2 x 16 pos ----
    const float* zimg = z + img * (DDIM * 1024) + p0;
#pragma unroll 1
    for (int c = 0; c < 2; ++c) {
        // stage 16 positions x 256 d as fp32 [16][ZS]
#pragma unroll
        for (int jj = 0; jj < 4; ++jj) {
            const int f4 = t + jj * 256;     // 0..1023
            const int d  = f4 >> 2;          // 0..255
            const int p4 = f4 & 3;           // float4 group (4 positions)
            const float4 v = *(const float4*)&zimg[d * 1024 + c * 16 + p4 * 4];
            sm.Zs[(p4 * 4 + 0) * ZS + d] = v.x;
            sm.Zs[(p4 * 4 + 1) * ZS + d] = v.y;
            sm.Zs[(p4 * 4 + 2) * ZS + d] = v.z;
            sm.Zs[(p4 * 4 + 3) * ZS + d] = v.w;
        }
        __syncthreads();
        if (t < 128) {
            const int pl = t >> 3, slot = t & 7;
            const float* zr = &sm.Zs[pl * ZS];

            // numpy-exact zsq: slot chains + xor butterfly, halves joined last
            float h0 = sqr_rn(zr[slot]);
            float h1 = sqr_rn(zr[128 + slot]);
#pragma unroll
            for (int i = 1; i < 16; ++i) {
                h0 = add_rn(h0, sqr_rn(zr[slot + 8 * i]));
                h1 = add_rn(h1, sqr_rn(zr[128 + slot + 8 * i]));
            }
#pragma unroll
            for (int m = 1; m <= 4; m <<= 1) {
                h0 = add_rn(h0, __shfl_xor(h0, m));
                h1 = add_rn(h1, __shfl_xor(h1, m));
            }
            const float zq = add_rn(h0, h1);

            const int code = (int)(unsigned)(redL[(c * 16 + pl) * 8 + slot] & 0xffffffffULL);
            const float* wr = W + code * DDIM;
            // sequential fma chain over d ascending — bit-identical to verified path
            float M = 0.f;
#pragma unroll 8
            for (int d4 = 0; d4 < 64; ++d4) {
                const float4 zv = *(const float4*)&zr[d4 * 4];
                const float4 wv = *(const float4*)&wr[d4 * 4];
                M = fmaf(zv.x, wv.x, M);
                M = fmaf(zv.y, wv.y, M);
                M = fmaf(zv.z, wv.z, M);
                M = fmaf(zv.w, wv.w, M);
            }
            const float s = add_rn(fmaf(-2.f, M, zq), wsq[code]);
            u64 v = ((u64)__float_as_uint(s) << 32) | (unsigned)code;
#pragma unroll
            for (int m = 1; m <= 4; m <<= 1) {
                const u64 o = __shfl_xor(v, m);
                if (o < v) v = o;
            }
            if (slot == 0) out[img * 1024 + p0 + c * 16 + pl] = (int)(unsigned)(v & 0xffffffffULL);
        }
        __syncthreads();   // protect Zs reuse for next chunk
    }
}

extern "C" void kernel_launch(void* const* d_in, const int* in_sizes, int n_in,
                              void* d_out, int out_size, void* d_ws, size_t ws_size,
                              hipStream_t stream) {
    const float* z = (const float*)d_in[0];   // [32, 256, 32, 32] NCHW
    const float* W = (const float*)d_in[1];   // [1024, 256]
    int* out = (int*)d_out;                   // [32768] int32 indices

    char* ws = (char*)d_ws;
    float*          wsq   = (float*)ws;                  //   4 KB @ 0
    unsigned short* wb16t = (unsigned short*)(ws + 4096); // 512 KB

    wprep<<<KCODES / 16, 256, 0, stream>>>(W, wsq, wb16t);
    vq_fused<<<NPOS / 32, 256, 0, stream>>>(z, W, wsq, wb16t, out);
}

// Round 7
// 143.835 us; speedup vs baseline: 1.2435x; 1.0638x over previous
//
#include <hip/hip_runtime.h>

#define NPOS 32768   // 32 * 32 * 32 positions
#define DDIM 256
#define KCODES 1024

typedef __attribute__((ext_vector_type(8))) short bf16x8;
typedef __attribute__((ext_vector_type(4))) float f32x4;
typedef unsigned long long u64;

// ---- fp32 ops with anti-contraction barriers (replicate numpy rounding) ----
__device__ __forceinline__ float sqr_rn(float x) {
    float r = x * x;
    asm volatile("" : "+v"(r));
    return r;
}
__device__ __forceinline__ float add_rn(float a, float b) {
    float r = a + b;
    asm volatile("" : "+v"(r));
    return r;
}

// fp32 -> bf16 round-to-nearest-even (verbatim from verified kernel)
__device__ __forceinline__ unsigned short f2bf(float x) {
    unsigned u = __float_as_uint(x);
    return (unsigned short)((u + 0x7fffu + ((u >> 16) & 1u)) >> 16);
}

// monotone pack: float score -> order-preserving u32, | code in low bits
__device__ __forceinline__ u64 packm(float s, int code) {
    unsigned b = __float_as_uint(s);
    unsigned mm = ((unsigned)((int)b >> 31)) | 0x80000000u;
    return ((u64)(b ^ mm) << 32) | (unsigned)code;
}

// ---------------- wprep: wsq + W bf16 tiled (verbatim from verified prep) ----------------
__global__ __launch_bounds__(256) void wprep(const float* __restrict__ W,
                                             float* __restrict__ wsq,
                                             unsigned short* __restrict__ wb16t) {
    const int t   = threadIdx.x;
    const int bid = blockIdx.x;
    const int row = bid * 16 + (t >> 4);
    const int j   = t & 15;
    const float* base = W + row * DDIM + (j & 7) + (j >> 3) * 128;
    float r = sqr_rn(base[0]);
#pragma unroll
    for (int i = 1; i < 16; ++i) r = add_rn(r, sqr_rn(base[i * 8]));
#pragma unroll
    for (int m = 1; m <= 8; m <<= 1) r = add_rn(r, __shfl_xor(r, m));
    if (j == 0) wsq[row] = r;
#pragma unroll
    for (int jj = 0; jj < 2; ++jj) {
        const int u  = t + jj * 256;      // 512 units = 16 rows x 32 k8
        const int n  = bid * 16 + (u >> 5);
        const int k8 = u & 31;
        const float4 f0 = *(const float4*)&W[n * DDIM + k8 * 8];
        const float4 f1 = *(const float4*)&W[n * DDIM + k8 * 8 + 4];
        bf16x8 o;
        o[0] = (short)f2bf(f0.x); o[1] = (short)f2bf(f0.y);
        o[2] = (short)f2bf(f0.z); o[3] = (short)f2bf(f0.w);
        o[4] = (short)f2bf(f1.x); o[5] = (short)f2bf(f1.y);
        o[6] = (short)f2bf(f1.z); o[7] = (short)f2bf(f1.w);
        const int kk = k8 >> 2, kq = k8 & 3;
        *(bf16x8*)&wb16t[(n >> 8) * 65536 + kk * 8192 + kq * 2048 + (n & 255) * 8] = o;
    }
}

// ---------------- fused: z->bf16 LDS stage + high-ILP MFMA GEMM + top-2 + exact rescore ----------------
// Grid 512: one block per 64 positions, 256 threads (4 waves as 2M x 2N).
// Key change vs r6: per-wave tile 32 rows x 128 cols, acc[2][8] -> 16 MFMAs
// per kk with ONE vmcnt wait (r6: 8 MFMAs per wait). This is the r0 gemm
// structure (proven <43 us unfused) rebuilt inside the fused kernel.
// Phase A: stage z [64 pos x 256 d] bf16 A-tile in LDS (same f2bf/tiling).
// Phase B: 4 n-panels of 256 codes; B ping-pong 8-frag register dbuf; A from
//          LDS on demand; per-panel scan -> tournament -> redP -> merge to
//          candL (top-2 per panel per row, exact; r0 semantics).
// Phase C: numpy-bit-exact rescore (verbatim), 2 chunks of 32 positions.
#define ZS 260   // floats per Zs row (bank-spread, as verified)
__global__ __launch_bounds__(256)
void vq_fused(const float* __restrict__ z,
              const float* __restrict__ W,
              const float* __restrict__ wsq,
              const unsigned short* __restrict__ wb16t,
              int* __restrict__ out) {
    union Sm {
        unsigned short At[16384];   // 32 KB bf16 A-tile [k8(32)][m(64)][e(8)]
        float          Zs[32 * ZS]; // 33.3 KB fp32 rescore tile (Phase C only)
    };
    __shared__ Sm  sm;
    __shared__ u64 redP[64 * 4];    // 2 KB: [row][nhalf(2)][2] per-panel scratch
    __shared__ u64 candL[64 * 8];   // 4 KB: [row][panel(4)][2] = 8 candidates

    const int t   = threadIdx.x;
    const int bid = blockIdx.x;
    const int img = bid >> 4;           // 16 blocks per image
    const int p0  = (bid & 15) * 64;    // first position within image

    // ---- Phase A: z -> bf16 A-tile in LDS ----
    {
        const float* zbase = z + img * (DDIM * 1024) + p0;
#pragma unroll
        for (int jj = 0; jj < 8; ++jj) {
            const int u_ = t + jj * 256;     // 2048 units = 64 m x 32 k8
            const int m  = u_ & 63;
            const int k8 = u_ >> 6;
            const float* src = zbase + k8 * 8192 + m;   // d = k8*8+e, stride 1024 floats
            bf16x8 o;
#pragma unroll
            for (int e = 0; e < 8; ++e) o[e] = (short)f2bf(src[e * 1024]);
            *(bf16x8*)&sm.At[k8 * 512 + m * 8] = o;     // byte addr k8*1024 + m*16
        }
    }
    __syncthreads();

    // ---- Phase B: GEMM over 4 n-panels, 16 MFMA per kk per wave ----
    const int w  = t >> 6;
    const int l  = t & 63;
    const int ln = l & 15;
    const int q  = l >> 4;
    const int mw = (w & 1) * 32;    // m-half
    const int nh = w >> 1;          // n-half
    const int nw = nh * 128;

    const char* aBase = (const char*)sm.At + q * 1024 + (mw + ln) * 16;
    const char* bBase = (const char*)wb16t + q * 4096 + (nw + ln) * 16;

#pragma unroll 1
    for (int nblk = 0; nblk < 4; ++nblk) {
        const int n0 = nblk * 256;
        float wq[8];
#pragma unroll
        for (int nf = 0; nf < 8; ++nf) wq[nf] = wsq[n0 + nw + nf * 16 + ln];

        f32x4 acc[2][8];
#pragma unroll
        for (int a = 0; a < 2; ++a)
#pragma unroll
            for (int b = 0; b < 8; ++b) acc[a][b] = (f32x4)(0.f);

        const char* bP = bBase + nblk * 131072;
        bf16x8 bA[8], bB[8];
#pragma unroll
        for (int nf = 0; nf < 8; ++nf) bA[nf] = *(const bf16x8*)(bP + nf * 256);

        // kk ping-pong: even kk uses bA (prefetch kk+1 -> bB),
        //               odd  kk uses bB (prefetch kk+2 -> bA). Order kk=0..7.
#pragma unroll 1
        for (int kk2 = 0; kk2 < 4; ++kk2) {
            const int kkE = kk2 * 2;
#pragma unroll
            for (int nf = 0; nf < 8; ++nf)
                bB[nf] = *(const bf16x8*)(bP + (kkE + 1) * 16384 + nf * 256);
            {
                bf16x8 afr[2];
#pragma unroll
                for (int mf = 0; mf < 2; ++mf)
                    afr[mf] = *(const bf16x8*)(aBase + kkE * 4096 + mf * 256);
#pragma unroll
                for (int nf = 0; nf < 8; ++nf)
#pragma unroll
                    for (int mf = 0; mf < 2; ++mf)
                        acc[mf][nf] = __builtin_amdgcn_mfma_f32_16x16x32_bf16(
                            afr[mf], bA[nf], acc[mf][nf], 0, 0, 0);
            }
            if (kk2 < 3) {
#pragma unroll
                for (int nf = 0; nf < 8; ++nf)
                    bA[nf] = *(const bf16x8*)(bP + (kkE + 2) * 16384 + nf * 256);
            }
            {
                bf16x8 afr[2];
#pragma unroll
                for (int mf = 0; mf < 2; ++mf)
                    afr[mf] = *(const bf16x8*)(aBase + (kkE + 1) * 4096 + mf * 256);
#pragma unroll
                for (int nf = 0; nf < 8; ++nf)
#pragma unroll
                    for (int mf = 0; mf < 2; ++mf)
                        acc[mf][nf] = __builtin_amdgcn_mfma_f32_16x16x32_bf16(
                            afr[mf], bB[nf], acc[mf][nf], 0, 0, 0);
            }
        }

        // epilogue: score = wsq - 2*acc (row-const zsq dropped); exact top-2
        // per (row, 128-col wave slice) via scan + tournament -> redP
#pragma unroll
        for (int mf = 0; mf < 2; ++mf) {
#pragma unroll
            for (int reg = 0; reg < 4; ++reg) {
                const int row = mw + mf * 16 + q * 4 + reg;
                float s0 = 1e30f, s1 = 1e30f;
                int   i0 = 0,     i1 = 0;
#pragma unroll
                for (int nf = 0; nf < 8; ++nf) {
                    const float s  = fmaf(-2.f, acc[mf][nf][reg], wq[nf]);
                    const int   cc = n0 + nw + nf * 16 + ln;
                    if (s < s0)      { s1 = s0; i1 = i0; s0 = s; i0 = cc; }
                    else if (s < s1) { s1 = s; i1 = cc; }
                }
                u64 c0 = packm(s0, i0), c1 = packm(s1, i1);
#pragma unroll
                for (int m = 1; m <= 8; m <<= 1) {
                    const u64 o0 = __shfl_xor(c0, m);
                    const u64 o1 = __shfl_xor(c1, m);
                    const u64 hi = (c0 < o0) ? o0 : c0;
                    c0 = (c0 < o0) ? c0 : o0;
                    const u64 lo = (c1 < o1) ? c1 : o1;
                    c1 = (hi < lo) ? hi : lo;
                }
                if (ln == 0) {
                    redP[row * 4 + nh * 2]     = c0;
                    redP[row * 4 + nh * 2 + 1] = c1;
                }
            }
        }
        __syncthreads();
        if (t < 64) {   // merge 2 sorted n-half pairs -> panel top-2
            const u64 a = redP[t * 4],     b = redP[t * 4 + 1];
            const u64 c = redP[t * 4 + 2], d = redP[t * 4 + 3];
            const u64 m1 = (a < c) ? a : c;
            const u64 hi = (a < c) ? c : a;
            const u64 lo = (b < d) ? b : d;
            const u64 m2 = (hi < lo) ? hi : lo;
            candL[t * 8 + nblk * 2]     = m1;
            candL[t * 8 + nblk * 2 + 1] = m2;
        }
        __syncthreads();   // protects redP reuse; publishes candL
    }

    // ---- Phase C: exact numpy-bit rescore (verbatim arithmetic), 2 x 32 pos ----
    const float* zimg = z + img * (DDIM * 1024) + p0;
#pragma unroll 1
    for (int ch = 0; ch < 2; ++ch) {
#pragma unroll
        for (int jj = 0; jj < 8; ++jj) {
            const int f4 = t + jj * 256;
            const int d = f4 >> 3, p4 = f4 & 7;
            const float4 v = *(const float4*)&zimg[d * 1024 + ch * 32 + p4 * 4];
            sm.Zs[(p4 * 4 + 0) * ZS + d] = v.x;
            sm.Zs[(p4 * 4 + 1) * ZS + d] = v.y;
            sm.Zs[(p4 * 4 + 2) * ZS + d] = v.z;
            sm.Zs[(p4 * 4 + 3) * ZS + d] = v.w;
        }
        __syncthreads();
        {
            const int pl = t >> 3, slot = t & 7;
            const float* zr = &sm.Zs[pl * ZS];

            // numpy-exact zsq: slot chains + xor butterfly, halves joined last
            float h0 = sqr_rn(zr[slot]);
            float h1 = sqr_rn(zr[128 + slot]);
#pragma unroll
            for (int i = 1; i < 16; ++i) {
                h0 = add_rn(h0, sqr_rn(zr[slot + 8 * i]));
                h1 = add_rn(h1, sqr_rn(zr[128 + slot + 8 * i]));
            }
#pragma unroll
            for (int m = 1; m <= 4; m <<= 1) {
                h0 = add_rn(h0, __shfl_xor(h0, m));
                h1 = add_rn(h1, __shfl_xor(h1, m));
            }
            const float zq = add_rn(h0, h1);

            const int code = (int)(unsigned)(candL[(ch * 32 + pl) * 8 + slot] & 0xffffffffULL);
            const float* wr = W + code * DDIM;
            // sequential fma chain over d ascending — bit-identical to verified path
            float M = 0.f;
#pragma unroll 8
            for (int d4 = 0; d4 < 64; ++d4) {
                const float4 zv = *(const float4*)&zr[d4 * 4];
                const float4 wv = *(const float4*)&wr[d4 * 4];
                M = fmaf(zv.x, wv.x, M);
                M = fmaf(zv.y, wv.y, M);
                M = fmaf(zv.z, wv.z, M);
                M = fmaf(zv.w, wv.w, M);
            }
            const float s = add_rn(fmaf(-2.f, M, zq), wsq[code]);
            u64 v = ((u64)__float_as_uint(s) << 32) | (unsigned)code;
#pragma unroll
            for (int m = 1; m <= 4; m <<= 1) {
                const u64 o = __shfl_xor(v, m);
                if (o < v) v = o;
            }
            if (slot == 0) out[img * 1024 + p0 + ch * 32 + pl] = (int)(unsigned)(v & 0xffffffffULL);
        }
        __syncthreads();   // protect Zs reuse for next chunk
    }
}

extern "C" void kernel_launch(void* const* d_in, const int* in_sizes, int n_in,
                              void* d_out, int out_size, void* d_ws, size_t ws_size,
                              hipStream_t stream) {
    const float* z = (const float*)d_in[0];   // [32, 256, 32, 32] NCHW
    const float* W = (const float*)d_in[1];   // [1024, 256]
    int* out = (int*)d_out;                   // [32768] int32 indices

    char* ws = (char*)d_ws;
    float*          wsq   = (float*)ws;                  //   4 KB @ 0
    unsigned short* wb16t = (unsigned short*)(ws + 4096); // 512 KB

    wprep<<<KCODES / 16, 256, 0, stream>>>(W, wsq, wb16t);
    vq_fused<<<NPOS / 64, 256, 0, stream>>>(z, W, wsq, wb16t, out);
}